// Round 1
// baseline (1303.948 us; speedup 1.0000x reference)
//
#include <hip/hip_runtime.h>

#define NN 50000
#define NE 800000
#define DD 96
#define BN_EPS 1e-5

// ---------------- copy (float4) ----------------
__global__ __launch_bounds__(256) void copy_f4(const float4* __restrict__ s,
                                               float4* __restrict__ d, int n4) {
  int t = blockIdx.x * 256 + threadIdx.x;
  if (t < n4) d[t] = s[t];
}

// ---------------- edge message + scatter-add ----------------
// thread t -> edge e = t/96, feat d = t%96
// msg = relu(x[src] + (ea[e]*lw[d]+lb[d])); agg[dst] += msg (skip if <=0)
__global__ __launch_bounds__(256) void edge_msg(
    const float* __restrict__ xin, const float* __restrict__ ea,
    const float* __restrict__ lw, const float* __restrict__ lb,
    const int* __restrict__ src, const int* __restrict__ dst,
    float* __restrict__ agg) {
  int t = blockIdx.x * 256 + threadIdx.x;
  if (t >= NE * DD) return;
  int e = t / DD;
  int d = t - e * DD;
  float ev = fmaf(ea[e], lw[d], lb[d]);
  float m = xin[src[e] * DD + d] + ev;
  if (m > 0.0f) atomicAdd(&agg[dst[e] * DD + d], m);
}

// ---------------- GEMM + bias + relu ----------------
template <int K, int M>
__global__ __launch_bounds__(256) void gemm_relu(
    const float* __restrict__ in, const float* __restrict__ W,
    const float* __restrict__ b, float* __restrict__ h) {
  int t = blockIdx.x * 256 + threadIdx.x;
  if (t >= NN * M) return;
  int i = t / M;
  int j = t - i * M;
  const float* row = in + i * K;
  float acc = b[j];
#pragma unroll
  for (int k = 0; k < K; ++k) acc = fmaf(row[k], W[k * M + j], acc);
  h[t] = fmaxf(acc, 0.0f);
}

// GEMM over concat([in1(K1), in2(K2)]) without materializing the concat
template <int K1, int K2, int M>
__global__ __launch_bounds__(256) void gemm_relu2(
    const float* __restrict__ in1, const float* __restrict__ in2,
    const float* __restrict__ W, const float* __restrict__ b,
    float* __restrict__ h) {
  int t = blockIdx.x * 256 + threadIdx.x;
  if (t >= NN * M) return;
  int i = t / M;
  int j = t - i * M;
  const float* r1 = in1 + i * K1;
  const float* r2 = in2 + i * K2;
  float acc = b[j];
#pragma unroll
  for (int k = 0; k < K1; ++k) acc = fmaf(r1[k], W[k * M + j], acc);
#pragma unroll
  for (int k = 0; k < K2; ++k) acc = fmaf(r2[k], W[(K1 + k) * M + j], acc);
  h[t] = fmaxf(acc, 0.0f);
}

// ---------------- per-column sum / sumsq ----------------
template <int M, int TPB>
__global__ void col_stats(const float* __restrict__ h,
                          double* __restrict__ stats /* [2*M] */) {
  constexpr int RPI = TPB / M;  // rows per block-iteration
  __shared__ float ssum[TPB];
  __shared__ float ssq[TPB];
  int t = threadIdx.x;
  int j = t % M;
  int r0 = t / M;
  float s = 0.0f, q = 0.0f;
  for (int row = blockIdx.x * RPI + r0; row < NN; row += gridDim.x * RPI) {
    float v = h[row * M + j];
    s += v;
    q += v * v;
  }
  ssum[t] = s;
  ssq[t] = q;
  __syncthreads();
  for (int st = TPB / 2; st >= M; st >>= 1) {
    if (t < st) {
      ssum[t] += ssum[t + st];
      ssq[t] += ssq[t + st];
    }
    __syncthreads();
  }
  if (t < M) {
    atomicAdd(&stats[j], (double)ssum[t]);
    atomicAdd(&stats[M + j], (double)ssq[t]);
  }
}

// ---------------- BN coeffs: scale = g*rsqrt(var+eps), shift = beta - mu*scale
template <int M>
__global__ void bn_coeffs(const double* __restrict__ stats,
                          const float* __restrict__ g,
                          const float* __restrict__ beta,
                          float* __restrict__ coeff /* [2*M] */) {
  int j = threadIdx.x;
  if (j >= M) return;
  double mu = stats[j] / (double)NN;
  double var = stats[M + j] / (double)NN - mu * mu;
  double inv = 1.0 / sqrt(var + (double)BN_EPS);
  double scale = (double)g[j] * inv;
  coeff[j] = (float)scale;
  coeff[M + j] = (float)((double)beta[j] - mu * scale);
}

// ---------------- BN normalize (optional dual write) ----------------
template <int M>
__global__ __launch_bounds__(256) void bn_norm(
    const float* __restrict__ h, const float* __restrict__ coeff,
    float* __restrict__ out, float* __restrict__ out2) {
  int t = blockIdx.x * 256 + threadIdx.x;
  if (t >= NN * M) return;
  int j = t % M;
  float v = fmaf(h[t], coeff[j], coeff[M + j]);
  out[t] = v;
  if (out2) out2[t] = v;
}

extern "C" void kernel_launch(void* const* d_in, const int* in_sizes, int n_in,
                              void* d_out, int out_size, void* d_ws,
                              size_t ws_size, hipStream_t stream) {
  const float* x = (const float*)d_in[0];
  const float* ea = (const float*)d_in[1];
  const int* ei = (const int*)d_in[2];
  const int* src = ei;
  const int* dst = ei + NE;
  const float* lin_w = (const float*)d_in[3];
  const float* lin_b = (const float*)d_in[4];
  const float* c1_w = (const float*)d_in[5];
  const float* c1_b = (const float*)d_in[6];
  const float* c1_g = (const float*)d_in[7];
  const float* c1_be = (const float*)d_in[8];
  const float* c2_w = (const float*)d_in[9];
  const float* c2_b = (const float*)d_in[10];
  const float* c2_g = (const float*)d_in[11];
  const float* c2_be = (const float*)d_in[12];
  const float* l1_w = (const float*)d_in[13];
  const float* l1_b = (const float*)d_in[14];
  const float* l1_g = (const float*)d_in[15];
  const float* l1_be = (const float*)d_in[16];
  const float* ma_w = (const float*)d_in[17];
  const float* ma_b = (const float*)d_in[18];
  const float* ma_g = (const float*)d_in[19];
  const float* ma_be = (const float*)d_in[20];
  const float* mb_w = (const float*)d_in[21];
  const float* mb_b = (const float*)d_in[22];
  const float* mb_g = (const float*)d_in[23];
  const float* mb_be = (const float*)d_in[24];

  float* ws = (float*)d_ws;
  float* bufA = ws;                  // [NN*96] agg / x3
  float* bufB = bufA + NN * DD;      // [NN*96] h scratch
  float* x1 = bufB + NN * DD;        // [NN*96]
  float* x2 = x1 + NN * DD;          // [NN*64]
  double* stats = (double*)(x2 + NN * 64);  // 5 layers x 192 doubles
  float* coeff = (float*)(stats + 5 * 192); // 192 floats, reused

  hipMemsetAsync(stats, 0, 5 * 192 * sizeof(double), stream);

  const int nElem96 = NN * 96, nElem64 = NN * 64, nElem16 = NN * 16;
  const int gemm96 = (nElem96 + 255) / 256;
  const int gemm64 = (nElem64 + 255) / 256;
  const int gemm16 = (nElem16 + 255) / 256;
  const int edgeBlocks = (NE * DD + 255) / 256;
  const int n4 = NN * DD / 4;

  // ---- conv1 ----
  copy_f4<<<(n4 + 255) / 256, 256, 0, stream>>>((const float4*)x,
                                                (float4*)bufA, n4);
  edge_msg<<<edgeBlocks, 256, 0, stream>>>(x, ea, lin_w, lin_b, src, dst, bufA);
  gemm_relu<96, 96><<<gemm96, 256, 0, stream>>>(bufA, c1_w, c1_b, bufB);
  col_stats<96, 192><<<256, 192, 0, stream>>>(bufB, stats);
  bn_coeffs<96><<<1, 96, 0, stream>>>(stats, c1_g, c1_be, coeff);
  // write x1, and also init conv2's agg (bufA) = x1
  bn_norm<96><<<gemm96, 256, 0, stream>>>(bufB, coeff, x1, bufA);

  // ---- conv2 ----
  edge_msg<<<edgeBlocks, 256, 0, stream>>>(x1, ea, lin_w, lin_b, src, dst,
                                           bufA);
  gemm_relu<96, 64><<<gemm64, 256, 0, stream>>>(bufA, c2_w, c2_b, bufB);
  col_stats<64, 256><<<256, 256, 0, stream>>>(bufB, stats + 192);
  bn_coeffs<64><<<1, 64, 0, stream>>>(stats + 192, c2_g, c2_be, coeff);
  bn_norm<64><<<gemm64, 256, 0, stream>>>(bufB, coeff, x2, nullptr);

  // ---- lin1 on concat([x1,x2]) ----
  gemm_relu2<96, 64, 96><<<gemm96, 256, 0, stream>>>(x1, x2, l1_w, l1_b, bufB);
  col_stats<96, 192><<<256, 192, 0, stream>>>(bufB, stats + 384);
  bn_coeffs<96><<<1, 96, 0, stream>>>(stats + 384, l1_g, l1_be, coeff);
  bn_norm<96><<<gemm96, 256, 0, stream>>>(bufB, coeff, bufA, nullptr);

  // ---- mlp1a ----
  gemm_relu<96, 96><<<gemm96, 256, 0, stream>>>(bufA, ma_w, ma_b, bufB);
  col_stats<96, 192><<<256, 192, 0, stream>>>(bufB, stats + 576);
  bn_coeffs<96><<<1, 96, 0, stream>>>(stats + 576, ma_g, ma_be, coeff);
  bn_norm<96><<<gemm96, 256, 0, stream>>>(bufB, coeff, x1, nullptr);

  // ---- mlp1b -> out ----
  gemm_relu<96, 16><<<gemm16, 256, 0, stream>>>(x1, mb_w, mb_b, bufB);
  col_stats<16, 256><<<256, 256, 0, stream>>>(bufB, stats + 768);
  bn_coeffs<16><<<1, 16, 0, stream>>>(stats + 768, mb_g, mb_be, coeff);
  bn_norm<16><<<gemm16, 256, 0, stream>>>(bufB, coeff, (float*)d_out, nullptr);
}

// Round 2
// 1057.888 us; speedup vs baseline: 1.2326x; 1.2326x over previous
//
#include <hip/hip_runtime.h>

#define NN 50000
#define NE 800000
#define DD 96
#define BN_EPS 1e-5

// ============ CSR build ============
__global__ __launch_bounds__(256) void hist_k(const int* __restrict__ dst,
                                              int* __restrict__ counts) {
  int e = blockIdx.x * 256 + threadIdx.x;
  if (e < NE) atomicAdd(&counts[dst[e]], 1);
}

// one-block exclusive scan over counts[NN] -> rowstart[NN+1]
__global__ void exscan_k(const int* __restrict__ counts,
                         int* __restrict__ rowstart) {
  __shared__ int part[1024];
  int tid = threadIdx.x;
  const int CH = (NN + 1023) / 1024;  // 49
  int lo = tid * CH, hi = min(lo + CH, NN);
  int s = 0;
  for (int i = lo; i < hi; i++) s += counts[i];
  part[tid] = s;
  __syncthreads();
  for (int off = 1; off < 1024; off <<= 1) {
    int t = (tid >= off) ? part[tid - off] : 0;
    __syncthreads();
    part[tid] += t;
    __syncthreads();
  }
  int run = (tid == 0) ? 0 : part[tid - 1];
  for (int i = lo; i < hi; i++) {
    rowstart[i] = run;
    run += counts[i];
  }
  if (tid == 1023) rowstart[NN] = run;
}

// scatter packed (src, edge_attr_value) by dst
__global__ __launch_bounds__(256) void scatter_k(
    const int* __restrict__ src, const int* __restrict__ dst,
    const float* __restrict__ ea, const int* __restrict__ rowstart,
    int* __restrict__ cursor, int2* __restrict__ pack) {
  int e = blockIdx.x * 256 + threadIdx.x;
  if (e >= NE) return;
  int d = dst[e];
  int p = rowstart[d] + atomicAdd(&cursor[d], 1);
  int2 v;
  v.x = src[e];
  v.y = __float_as_int(ea[e]);
  pack[p] = v;
}

// ============ CSR aggregation: out[n] = xin[n] + sum relu(xin[src]+e) ======
__global__ __launch_bounds__(256) void agg_csr(
    const float* __restrict__ xin, const float* __restrict__ lw,
    const float* __restrict__ lb, const int* __restrict__ rowstart,
    const int2* __restrict__ pack, float* __restrict__ out) {
  int t = blockIdx.x * 256 + threadIdx.x;
  if (t >= NN * DD) return;
  int n = t / DD, d = t - n * DD;
  float lwd = lw[d], lbd = lb[d];
  float acc = xin[t];
  int beg = rowstart[n], end = rowstart[n + 1];
  for (int i = beg; i < end; i++) {
    int2 p = pack[i];
    float m = xin[p.x * DD + d] + fmaf(__int_as_float(p.y), lwd, lbd);
    acc += fmaxf(m, 0.0f);
  }
  out[t] = acc;
}

// ============ fused GEMM + relu + column stats ============
// 192 threads, grid-stride over rows; j = tid%M
template <int K, int M>
__global__ __launch_bounds__(192) void gemm_stats(
    const float* __restrict__ in, const float* __restrict__ W,
    const float* __restrict__ b, float* __restrict__ h,
    double* __restrict__ stats) {
  constexpr int R = 192 / M;
  int tid = threadIdx.x;
  int j = tid % M, r0 = tid / M;
  float bj = b[j];
  float s = 0.0f, q = 0.0f;
  for (int row = blockIdx.x * R + r0; row < NN; row += gridDim.x * R) {
    const float4* rp = (const float4*)(in + row * K);
    float a0 = bj, a1 = 0.f, a2 = 0.f, a3 = 0.f;
#pragma unroll
    for (int k4 = 0; k4 < K / 4; k4++) {
      float4 r4 = rp[k4];
      a0 = fmaf(r4.x, W[(4 * k4 + 0) * M + j], a0);
      a1 = fmaf(r4.y, W[(4 * k4 + 1) * M + j], a1);
      a2 = fmaf(r4.z, W[(4 * k4 + 2) * M + j], a2);
      a3 = fmaf(r4.w, W[(4 * k4 + 3) * M + j], a3);
    }
    float acc = fmaxf((a0 + a1) + (a2 + a3), 0.0f);
    h[row * M + j] = acc;
    s += acc;
    q += acc * acc;
  }
  __shared__ float ls[192], lq[192];
  ls[tid] = s;
  lq[tid] = q;
  __syncthreads();
  if (tid < M) {
    float ts = 0.f, tq = 0.f;
#pragma unroll
    for (int r = 0; r < R; r++) {
      ts += ls[r * M + tid];
      tq += lq[r * M + tid];
    }
    atomicAdd(&stats[tid], (double)ts);
    atomicAdd(&stats[M + tid], (double)tq);
  }
}

// two-input (concat) variant
template <int K1, int K2, int M>
__global__ __launch_bounds__(192) void gemm2_stats(
    const float* __restrict__ in1, const float* __restrict__ in2,
    const float* __restrict__ W, const float* __restrict__ b,
    float* __restrict__ h, double* __restrict__ stats) {
  constexpr int R = 192 / M;
  int tid = threadIdx.x;
  int j = tid % M, r0 = tid / M;
  float bj = b[j];
  float s = 0.0f, q = 0.0f;
  for (int row = blockIdx.x * R + r0; row < NN; row += gridDim.x * R) {
    const float4* rp1 = (const float4*)(in1 + row * K1);
    const float4* rp2 = (const float4*)(in2 + row * K2);
    float a0 = bj, a1 = 0.f, a2 = 0.f, a3 = 0.f;
#pragma unroll
    for (int k4 = 0; k4 < K1 / 4; k4++) {
      float4 r4 = rp1[k4];
      a0 = fmaf(r4.x, W[(4 * k4 + 0) * M + j], a0);
      a1 = fmaf(r4.y, W[(4 * k4 + 1) * M + j], a1);
      a2 = fmaf(r4.z, W[(4 * k4 + 2) * M + j], a2);
      a3 = fmaf(r4.w, W[(4 * k4 + 3) * M + j], a3);
    }
#pragma unroll
    for (int k4 = 0; k4 < K2 / 4; k4++) {
      float4 r4 = rp2[k4];
      a0 = fmaf(r4.x, W[(K1 + 4 * k4 + 0) * M + j], a0);
      a1 = fmaf(r4.y, W[(K1 + 4 * k4 + 1) * M + j], a1);
      a2 = fmaf(r4.z, W[(K1 + 4 * k4 + 2) * M + j], a2);
      a3 = fmaf(r4.w, W[(K1 + 4 * k4 + 3) * M + j], a3);
    }
    float acc = fmaxf((a0 + a1) + (a2 + a3), 0.0f);
    h[row * M + j] = acc;
    s += acc;
    q += acc * acc;
  }
  __shared__ float ls[192], lq[192];
  ls[tid] = s;
  lq[tid] = q;
  __syncthreads();
  if (tid < M) {
    float ts = 0.f, tq = 0.f;
#pragma unroll
    for (int r = 0; r < R; r++) {
      ts += ls[r * M + tid];
      tq += lq[r * M + tid];
    }
    atomicAdd(&stats[tid], (double)ts);
    atomicAdd(&stats[M + tid], (double)tq);
  }
}

// ============ BN coeffs: scale/shift from sums ============
template <int M>
__global__ void bn_coeffs(const double* __restrict__ stats,
                          const float* __restrict__ g,
                          const float* __restrict__ beta,
                          float* __restrict__ coeff) {
  int j = threadIdx.x;
  if (j >= M) return;
  double mu = stats[j] / (double)NN;
  double var = stats[M + j] / (double)NN - mu * mu;
  double inv = 1.0 / sqrt(var + (double)BN_EPS);
  double scale = (double)g[j] * inv;
  coeff[j] = (float)scale;
  coeff[M + j] = (float)((double)beta[j] - mu * scale);
}

// ============ fold BN of previous layer into next-layer weights ============
// Wf[k,j] = (k in [KS,KS+KC) ? coeff[k-KS] : 1) * W[k,j]
// bf[j]   = b[j] + sum_{k in scaled} coeff[KC + (k-KS)] * W[k,j]
template <int KTOT, int KS, int KC, int M>
__global__ void fold_w(const float* __restrict__ W, const float* __restrict__ b,
                       const float* __restrict__ coeff, float* __restrict__ Wf,
                       float* __restrict__ bf) {
  int j = threadIdx.x;
  if (j >= M) return;
  float acc = b[j];
  for (int k = 0; k < KTOT; k++) {
    float w = W[k * M + j];
    if (k >= KS && k < KS + KC) {
      int c = k - KS;
      Wf[k * M + j] = coeff[c] * w;
      acc += coeff[KC + c] * w;
    } else {
      Wf[k * M + j] = w;
    }
  }
  bf[j] = acc;
}

// ============ BN normalize (float4) ============
template <int M>
__global__ __launch_bounds__(256) void bn_norm4(const float4* __restrict__ h,
                                                const float* __restrict__ coeff,
                                                float4* __restrict__ out) {
  int t = blockIdx.x * 256 + threadIdx.x;
  if (t >= NN * M / 4) return;
  float4 v = h[t];
  int j0 = (4 * t) % M;
  float4 o;
  o.x = fmaf(v.x, coeff[j0 + 0], coeff[M + j0 + 0]);
  o.y = fmaf(v.y, coeff[j0 + 1], coeff[M + j0 + 1]);
  o.z = fmaf(v.z, coeff[j0 + 2], coeff[M + j0 + 2]);
  o.w = fmaf(v.w, coeff[j0 + 3], coeff[M + j0 + 3]);
  out[t] = o;
}

// ============ launch ============
static inline char* alignup(char* p, size_t a) {
  return (char*)(((uintptr_t)p + a - 1) & ~(uintptr_t)(a - 1));
}

extern "C" void kernel_launch(void* const* d_in, const int* in_sizes, int n_in,
                              void* d_out, int out_size, void* d_ws,
                              size_t ws_size, hipStream_t stream) {
  const float* x = (const float*)d_in[0];
  const float* ea = (const float*)d_in[1];
  const int* ei = (const int*)d_in[2];
  const int* src = ei;
  const int* dst = ei + NE;
  const float* lin_w = (const float*)d_in[3];
  const float* lin_b = (const float*)d_in[4];
  const float* c1_w = (const float*)d_in[5];
  const float* c1_b = (const float*)d_in[6];
  const float* c1_g = (const float*)d_in[7];
  const float* c1_be = (const float*)d_in[8];
  const float* c2_w = (const float*)d_in[9];
  const float* c2_b = (const float*)d_in[10];
  const float* c2_g = (const float*)d_in[11];
  const float* c2_be = (const float*)d_in[12];
  const float* l1_w = (const float*)d_in[13];
  const float* l1_b = (const float*)d_in[14];
  const float* l1_g = (const float*)d_in[15];
  const float* l1_be = (const float*)d_in[16];
  const float* ma_w = (const float*)d_in[17];
  const float* ma_b = (const float*)d_in[18];
  const float* ma_g = (const float*)d_in[19];
  const float* ma_be = (const float*)d_in[20];
  const float* mb_w = (const float*)d_in[21];
  const float* mb_b = (const float*)d_in[22];
  const float* mb_g = (const float*)d_in[23];
  const float* mb_be = (const float*)d_in[24];

  char* p = (char*)d_ws;
  float* A = (float*)p;            p += (size_t)NN * 96 * 4;   // agg / h3
  float* H = (float*)p;            p += (size_t)NN * 96 * 4;   // h1 / h4
  float* X1 = (float*)p;           p += (size_t)NN * 96 * 4;
  float* H2 = (float*)p;           p += (size_t)NN * 64 * 4;
  float* H5 = (float*)p;           p += (size_t)NN * 16 * 4;
  float* Wf = (float*)p;           p += (size_t)160 * 96 * 4;
  float* bf = (float*)p;           p += 96 * 4;
  float* coeffs = (float*)p;       p += 5 * 192 * 4;           // c1..c5
  p = alignup(p, 256);
  // ---- zeroed region: counts, cursor, stats ----
  char* zbase = p;
  int* counts = (int*)p;           p += (size_t)NN * 4;
  int* cursor = (int*)p;           p += (size_t)NN * 4;
  double* stats = (double*)p;      p += (size_t)5 * 192 * 8;
  size_t zbytes = (size_t)(p - zbase);
  // ---- non-zeroed ----
  int* rowstart = (int*)p;         p += (size_t)(NN + 1) * 4;
  p = alignup(p, 8);
  int2* pack = (int2*)p;           p += (size_t)NE * 8;

  float* c1 = coeffs;
  float* c2 = coeffs + 192;
  float* c3 = coeffs + 384;
  float* c4 = coeffs + 576;
  float* c5 = coeffs + 768;

  hipMemsetAsync(zbase, 0, zbytes, stream);

  const int eb = (NE + 255) / 256;
  const int nb96 = (NN * 96 + 255) / 256;
  const int GB = 1024;  // gemm grid

  // ---- CSR build (shared by both convs) ----
  hist_k<<<eb, 256, 0, stream>>>(dst, counts);
  exscan_k<<<1, 1024, 0, stream>>>(counts, rowstart);
  scatter_k<<<eb, 256, 0, stream>>>(src, dst, ea, rowstart, cursor, pack);

  // ---- conv1 ----
  agg_csr<<<nb96, 256, 0, stream>>>(x, lin_w, lin_b, rowstart, pack, A);
  gemm_stats<96, 96><<<GB, 192, 0, stream>>>(A, c1_w, c1_b, H, stats);
  bn_coeffs<96><<<1, 96, 0, stream>>>(stats, c1_g, c1_be, c1);
  bn_norm4<96><<<(NN * 96 / 4 + 255) / 256, 256, 0, stream>>>(
      (const float4*)H, c1, (float4*)X1);

  // ---- conv2 ----
  agg_csr<<<nb96, 256, 0, stream>>>(X1, lin_w, lin_b, rowstart, pack, A);
  gemm_stats<96, 64><<<GB, 192, 0, stream>>>(A, c2_w, c2_b, H2, stats + 192);
  bn_coeffs<64><<<1, 64, 0, stream>>>(stats + 192, c2_g, c2_be, c2);

  // ---- lin1 on concat([x1_norm, h2 (BN folded into W)]) ----
  fold_w<160, 96, 64, 96><<<1, 96, 0, stream>>>(l1_w, l1_b, c2, Wf, bf);
  gemm2_stats<96, 64, 96><<<GB, 192, 0, stream>>>(X1, H2, Wf, bf, A,
                                                  stats + 384);
  bn_coeffs<96><<<1, 96, 0, stream>>>(stats + 384, l1_g, l1_be, c3);

  // ---- mlp1a (BN3 folded) ----
  fold_w<96, 0, 96, 96><<<1, 96, 0, stream>>>(ma_w, ma_b, c3, Wf, bf);
  gemm_stats<96, 96><<<GB, 192, 0, stream>>>(A, Wf, bf, H, stats + 576);
  bn_coeffs<96><<<1, 96, 0, stream>>>(stats + 576, ma_g, ma_be, c4);

  // ---- mlp1b (BN4 folded) ----
  fold_w<96, 0, 96, 16><<<1, 16, 0, stream>>>(mb_w, mb_b, c4, Wf, bf);
  gemm_stats<96, 16><<<GB, 192, 0, stream>>>(H, Wf, bf, H5, stats + 768);
  bn_coeffs<16><<<1, 16, 0, stream>>>(stats + 768, mb_g, mb_be, c5);
  bn_norm4<16><<<(NN * 16 / 4 + 255) / 256, 256, 0, stream>>>(
      (const float4*)H5, c5, (float4*)d_out);
}

// Round 3
// 819.010 us; speedup vs baseline: 1.5921x; 1.2917x over previous
//
#include <hip/hip_runtime.h>

#define NN 50000
#define NE 800000
#define DD 96
#define BN_EPS 1e-5

// ============ CSR build ============
__global__ __launch_bounds__(256) void hist_k(const int* __restrict__ dst,
                                              int* __restrict__ counts) {
  int e = blockIdx.x * 256 + threadIdx.x;
  if (e < NE) atomicAdd(&counts[dst[e]], 1);
}

__global__ void exscan_k(const int* __restrict__ counts,
                         int* __restrict__ rowstart) {
  __shared__ int part[1024];
  int tid = threadIdx.x;
  const int CH = (NN + 1023) / 1024;
  int lo = tid * CH, hi = min(lo + CH, NN);
  int s = 0;
  for (int i = lo; i < hi; i++) s += counts[i];
  part[tid] = s;
  __syncthreads();
  for (int off = 1; off < 1024; off <<= 1) {
    int t = (tid >= off) ? part[tid - off] : 0;
    __syncthreads();
    part[tid] += t;
    __syncthreads();
  }
  int run = (tid == 0) ? 0 : part[tid - 1];
  for (int i = lo; i < hi; i++) {
    rowstart[i] = run;
    run += counts[i];
  }
  if (tid == 1023) rowstart[NN] = run;
}

__global__ __launch_bounds__(256) void scatter_k(
    const int* __restrict__ src, const int* __restrict__ dst,
    const float* __restrict__ ea, const int* __restrict__ rowstart,
    int* __restrict__ cursor, int2* __restrict__ pack) {
  int e = blockIdx.x * 256 + threadIdx.x;
  if (e >= NE) return;
  int d = dst[e];
  int p = rowstart[d] + atomicAdd(&cursor[d], 1);
  int2 v;
  v.x = src[e];
  v.y = __float_as_int(ea[e]);
  pack[p] = v;
}

// ===== CSR aggregation, float4: thread = (node, 4 feats) =====
__global__ __launch_bounds__(256) void agg_csr4(
    const float4* __restrict__ xin4, const float* __restrict__ lw,
    const float* __restrict__ lb, const int* __restrict__ rowstart,
    const int2* __restrict__ pack, float4* __restrict__ out4) {
  int t = blockIdx.x * 256 + threadIdx.x;
  if (t >= NN * (DD / 4)) return;
  int n = t / (DD / 4), c4 = t - n * (DD / 4);
  float4 lw4 = ((const float4*)lw)[c4];
  float4 lb4 = ((const float4*)lb)[c4];
  float4 acc = xin4[t];
  int beg = rowstart[n], end = rowstart[n + 1];
  for (int i = beg; i < end; i++) {
    int2 p = pack[i];
    float ev = __int_as_float(p.y);
    float4 xs = xin4[p.x * (DD / 4) + c4];
    acc.x += fmaxf(xs.x + fmaf(ev, lw4.x, lb4.x), 0.0f);
    acc.y += fmaxf(xs.y + fmaf(ev, lw4.y, lb4.y), 0.0f);
    acc.z += fmaxf(xs.z + fmaf(ev, lw4.z, lb4.z), 0.0f);
    acc.w += fmaxf(xs.w + fmaf(ev, lw4.w, lb4.w), 0.0f);
  }
  out4[t] = acc;
}

// ============ tiled GEMM + bias + relu + column stats ============
// 384 threads. Thread owns NR rows x 4 cols. W staged in LDS (96-row
// K-chunks), input tile staged in LDS (coalesced float4).
template <int K1, int K2, int M, int NR>
__global__ __launch_bounds__(384) void gemm_tile(
    const float* __restrict__ in1, const float* __restrict__ in2,
    const float* __restrict__ W, const float* __restrict__ b,
    float* __restrict__ h, double* __restrict__ stats, int rowTiles) {
  constexpr int K = K1 + K2;
  constexpr int C4 = M / 4;        // float4 col groups
  constexpr int RP = 384 / C4;     // row threads per pass
  constexpr int TROWS = RP * NR;   // rows per tile
  constexpr int KCH = 96;          // K rows of W staged at once
  constexpr int NCH = (K + KCH - 1) / KCH;
  constexpr int WSZ = (K < KCH ? K : KCH) * M;
  constexpr int F4R = K / 4;       // float4 per input row

  __shared__ float Wl[WSZ];
  __shared__ float inl[TROWS * K];

  int tid = threadIdx.x;
  int c4 = tid % C4, r0 = tid / C4;
  float4 bj = ((const float4*)b)[c4];
  float s0 = 0.f, s1 = 0.f, s2 = 0.f, s3 = 0.f;
  float q0 = 0.f, q1 = 0.f, q2 = 0.f, q3 = 0.f;

  if (NCH == 1) {  // stage W once
    for (int idx = tid; idx < K * M / 4; idx += 384)
      ((float4*)Wl)[idx] = ((const float4*)W)[idx];
  }

  for (int tile = blockIdx.x; tile < rowTiles; tile += gridDim.x) {
    int rowBase = tile * TROWS;
    __syncthreads();  // prev readers done (and W ready on iter 0)
    // stage input tile
    for (int idx = tid; idx < TROWS * F4R; idx += 384) {
      int r = idx / F4R, c = idx - r * F4R;
      int rg = rowBase + r;
      float4 v = make_float4(0.f, 0.f, 0.f, 0.f);
      if (rg < NN) {
        if (K2 > 0) {
          v = (c < K1 / 4)
                  ? ((const float4*)(in1 + (size_t)rg * K1))[c]
                  : ((const float4*)(in2 + (size_t)rg * K2))[c - K1 / 4];
        } else {
          v = ((const float4*)(in1 + (size_t)rg * K1))[c];
        }
      }
      ((float4*)inl)[idx] = v;
    }

    float4 acc[NR];
#pragma unroll
    for (int rr = 0; rr < NR; rr++) acc[rr] = make_float4(0.f, 0.f, 0.f, 0.f);

    for (int ch = 0; ch < NCH; ch++) {
      int kbase = ch * KCH;
      int Kc = (K - kbase < KCH) ? (K - kbase) : KCH;
      if (NCH > 1) {
        __syncthreads();  // inl ready / prev W readers done
        for (int idx = tid; idx < Kc * M / 4; idx += 384)
          ((float4*)Wl)[idx] = ((const float4*)(W + kbase * M))[idx];
      }
      __syncthreads();  // W + inl ready
#pragma unroll 8
      for (int k = 0; k < Kc; k++) {
        float4 w4 = *(const float4*)&Wl[k * M + c4 * 4];
#pragma unroll
        for (int rr = 0; rr < NR; rr++) {
          float a = inl[(r0 + rr * RP) * K + kbase + k];
          acc[rr].x = fmaf(a, w4.x, acc[rr].x);
          acc[rr].y = fmaf(a, w4.y, acc[rr].y);
          acc[rr].z = fmaf(a, w4.z, acc[rr].z);
          acc[rr].w = fmaf(a, w4.w, acc[rr].w);
        }
      }
    }

#pragma unroll
    for (int rr = 0; rr < NR; rr++) {
      int rg = rowBase + r0 + rr * RP;
      if (rg < NN) {
        float4 o;
        o.x = fmaxf(acc[rr].x + bj.x, 0.f);
        o.y = fmaxf(acc[rr].y + bj.y, 0.f);
        o.z = fmaxf(acc[rr].z + bj.z, 0.f);
        o.w = fmaxf(acc[rr].w + bj.w, 0.f);
        ((float4*)h)[(size_t)rg * C4 + c4] = o;
        s0 += o.x; s1 += o.y; s2 += o.z; s3 += o.w;
        q0 += o.x * o.x; q1 += o.y * o.y; q2 += o.z * o.z; q3 += o.w * o.w;
      }
    }
  }

  // ---- stats reduction (reuse Wl; WSZ*4 >= 384*4*4 always) ----
  float* red = Wl;
  __syncthreads();
  red[tid * 4 + 0] = s0; red[tid * 4 + 1] = s1;
  red[tid * 4 + 2] = s2; red[tid * 4 + 3] = s3;
  __syncthreads();
  if (tid < C4) {
    double t0 = 0, t1 = 0, t2 = 0, t3 = 0;
    for (int rr = 0; rr < RP; rr++) {
      const float* rp = &red[(rr * C4 + tid) * 4];
      t0 += rp[0]; t1 += rp[1]; t2 += rp[2]; t3 += rp[3];
    }
    atomicAdd(&stats[tid * 4 + 0], t0);
    atomicAdd(&stats[tid * 4 + 1], t1);
    atomicAdd(&stats[tid * 4 + 2], t2);
    atomicAdd(&stats[tid * 4 + 3], t3);
  }
  __syncthreads();
  red[tid * 4 + 0] = q0; red[tid * 4 + 1] = q1;
  red[tid * 4 + 2] = q2; red[tid * 4 + 3] = q3;
  __syncthreads();
  if (tid < C4) {
    double t0 = 0, t1 = 0, t2 = 0, t3 = 0;
    for (int rr = 0; rr < RP; rr++) {
      const float* rp = &red[(rr * C4 + tid) * 4];
      t0 += rp[0]; t1 += rp[1]; t2 += rp[2]; t3 += rp[3];
    }
    atomicAdd(&stats[M + tid * 4 + 0], t0);
    atomicAdd(&stats[M + tid * 4 + 1], t1);
    atomicAdd(&stats[M + tid * 4 + 2], t2);
    atomicAdd(&stats[M + tid * 4 + 3], t3);
  }
}

// ============ BN coeffs ============
template <int M>
__global__ void bn_coeffs(const double* __restrict__ stats,
                          const float* __restrict__ g,
                          const float* __restrict__ beta,
                          float* __restrict__ coeff) {
  int j = threadIdx.x;
  if (j >= M) return;
  double mu = stats[j] / (double)NN;
  double var = stats[M + j] / (double)NN - mu * mu;
  double inv = 1.0 / sqrt(var + (double)BN_EPS);
  double scale = (double)g[j] * inv;
  coeff[j] = (float)scale;
  coeff[M + j] = (float)((double)beta[j] - mu * scale);
}

// ============ fold BN into next-layer weights ============
template <int KTOT, int KS, int KC, int M>
__global__ void fold_w(const float* __restrict__ W, const float* __restrict__ b,
                       const float* __restrict__ coeff, float* __restrict__ Wf,
                       float* __restrict__ bf) {
  int j = threadIdx.x;
  if (j >= M) return;
  float acc = b[j];
  for (int k = 0; k < KTOT; k++) {
    float w = W[k * M + j];
    if (k >= KS && k < KS + KC) {
      int c = k - KS;
      Wf[k * M + j] = coeff[c] * w;
      acc += coeff[KC + c] * w;
    } else {
      Wf[k * M + j] = w;
    }
  }
  bf[j] = acc;
}

// ============ BN normalize (float4) ============
template <int M>
__global__ __launch_bounds__(256) void bn_norm4(const float4* __restrict__ h,
                                                const float* __restrict__ coeff,
                                                float4* __restrict__ out) {
  int t = blockIdx.x * 256 + threadIdx.x;
  if (t >= NN * M / 4) return;
  float4 v = h[t];
  int j0 = (4 * t) % M;
  float4 o;
  o.x = fmaf(v.x, coeff[j0 + 0], coeff[M + j0 + 0]);
  o.y = fmaf(v.y, coeff[j0 + 1], coeff[M + j0 + 1]);
  o.z = fmaf(v.z, coeff[j0 + 2], coeff[M + j0 + 2]);
  o.w = fmaf(v.w, coeff[j0 + 3], coeff[M + j0 + 3]);
  out[t] = o;
}

static inline char* alignup(char* p, size_t a) {
  return (char*)(((uintptr_t)p + a - 1) & ~(uintptr_t)(a - 1));
}

extern "C" void kernel_launch(void* const* d_in, const int* in_sizes, int n_in,
                              void* d_out, int out_size, void* d_ws,
                              size_t ws_size, hipStream_t stream) {
  const float* x = (const float*)d_in[0];
  const float* ea = (const float*)d_in[1];
  const int* ei = (const int*)d_in[2];
  const int* src = ei;
  const int* dst = ei + NE;
  const float* lin_w = (const float*)d_in[3];
  const float* lin_b = (const float*)d_in[4];
  const float* c1_w = (const float*)d_in[5];
  const float* c1_b = (const float*)d_in[6];
  const float* c1_g = (const float*)d_in[7];
  const float* c1_be = (const float*)d_in[8];
  const float* c2_w = (const float*)d_in[9];
  const float* c2_b = (const float*)d_in[10];
  const float* c2_g = (const float*)d_in[11];
  const float* c2_be = (const float*)d_in[12];
  const float* l1_w = (const float*)d_in[13];
  const float* l1_b = (const float*)d_in[14];
  const float* l1_g = (const float*)d_in[15];
  const float* l1_be = (const float*)d_in[16];
  const float* ma_w = (const float*)d_in[17];
  const float* ma_b = (const float*)d_in[18];
  const float* ma_g = (const float*)d_in[19];
  const float* ma_be = (const float*)d_in[20];
  const float* mb_w = (const float*)d_in[21];
  const float* mb_b = (const float*)d_in[22];
  const float* mb_g = (const float*)d_in[23];
  const float* mb_be = (const float*)d_in[24];

  char* p = (char*)d_ws;
  float* A = (float*)p;            p += (size_t)NN * 96 * 4;
  float* H = (float*)p;            p += (size_t)NN * 96 * 4;
  float* X1 = (float*)p;           p += (size_t)NN * 96 * 4;
  float* H2 = (float*)p;           p += (size_t)NN * 64 * 4;
  float* H5 = (float*)p;           p += (size_t)NN * 16 * 4;
  float* Wf = (float*)p;           p += (size_t)160 * 96 * 4;
  float* bf = (float*)p;           p += 96 * 4;
  float* coeffs = (float*)p;       p += 5 * 192 * 4;
  p = alignup(p, 256);
  char* zbase = p;
  int* counts = (int*)p;           p += (size_t)NN * 4;
  int* cursor = (int*)p;           p += (size_t)NN * 4;
  double* stats = (double*)p;      p += (size_t)5 * 192 * 8;
  size_t zbytes = (size_t)(p - zbase);
  int* rowstart = (int*)p;         p += (size_t)(NN + 1) * 4;
  p = alignup(p, 8);
  int2* pack = (int2*)p;           p += (size_t)NE * 8;

  float* c1 = coeffs;
  float* c2 = coeffs + 192;
  float* c3 = coeffs + 384;
  float* c4 = coeffs + 576;
  float* c5 = coeffs + 768;

  hipMemsetAsync(zbase, 0, zbytes, stream);

  const int eb = (NE + 255) / 256;
  const int aggB = (NN * 24 + 255) / 256;

  // tiles: TROWS = (384/(M/4))*NR
  const int t96 = (NN + 31) / 32;    // M=96, NR=2 -> 32 rows
  const int t64 = (NN + 47) / 48;    // M=64, NR=2 -> 48 rows
  const int tl1 = (NN + 15) / 16;    // lin1: M=96, NR=1 -> 16 rows
  const int t16 = (NN + 95) / 96;    // M=16, NR=1 -> 96 rows
  const int G96 = min(t96, 768), G64 = min(t64, 768);
  const int GL1 = min(tl1, 768), G16 = min(t16, 768);

  // ---- CSR build ----
  hist_k<<<eb, 256, 0, stream>>>(dst, counts);
  exscan_k<<<1, 1024, 0, stream>>>(counts, rowstart);
  scatter_k<<<eb, 256, 0, stream>>>(src, dst, ea, rowstart, cursor, pack);

  // ---- conv1 ----
  agg_csr4<<<aggB, 256, 0, stream>>>((const float4*)x, lin_w, lin_b, rowstart,
                                     pack, (float4*)A);
  gemm_tile<96, 0, 96, 2><<<G96, 384, 0, stream>>>(A, nullptr, c1_w, c1_b, H,
                                                   stats, t96);
  bn_coeffs<96><<<1, 96, 0, stream>>>(stats, c1_g, c1_be, c1);
  bn_norm4<96><<<(NN * 96 / 4 + 255) / 256, 256, 0, stream>>>(
      (const float4*)H, c1, (float4*)X1);

  // ---- conv2 ----
  agg_csr4<<<aggB, 256, 0, stream>>>((const float4*)X1, lin_w, lin_b, rowstart,
                                     pack, (float4*)A);
  gemm_tile<96, 0, 64, 2><<<G64, 384, 0, stream>>>(A, nullptr, c2_w, c2_b, H2,
                                                   stats + 192, t64);
  bn_coeffs<64><<<1, 64, 0, stream>>>(stats + 192, c2_g, c2_be, c2);

  // ---- lin1 on concat([X1, H2(BN folded)]) ----
  fold_w<160, 96, 64, 96><<<1, 96, 0, stream>>>(l1_w, l1_b, c2, Wf, bf);
  gemm_tile<96, 64, 96, 1><<<GL1, 384, 0, stream>>>(X1, H2, Wf, bf, A,
                                                    stats + 384, tl1);
  bn_coeffs<96><<<1, 96, 0, stream>>>(stats + 384, l1_g, l1_be, c3);

  // ---- mlp1a (BN3 folded) ----
  fold_w<96, 0, 96, 96><<<1, 96, 0, stream>>>(ma_w, ma_b, c3, Wf, bf);
  gemm_tile<96, 0, 96, 2><<<G96, 384, 0, stream>>>(A, nullptr, Wf, bf, H,
                                                   stats + 576, t96);
  bn_coeffs<96><<<1, 96, 0, stream>>>(stats + 576, ma_g, ma_be, c4);

  // ---- mlp1b (BN4 folded) ----
  fold_w<96, 0, 96, 16><<<1, 16, 0, stream>>>(mb_w, mb_b, c4, Wf, bf);
  gemm_tile<96, 0, 16, 1><<<G16, 384, 0, stream>>>(H, nullptr, Wf, bf, H5,
                                                   stats + 768, t16);
  bn_coeffs<16><<<1, 16, 0, stream>>>(stats + 768, mb_g, mb_be, c5);
  bn_norm4<16><<<(NN * 16 / 4 + 255) / 256, 256, 0, stream>>>(
      (const float4*)H5, c5, (float4*)d_out);
}

// Round 4
// 445.228 us; speedup vs baseline: 2.9287x; 1.8395x over previous
//
#include <hip/hip_runtime.h>

#define NN 50000
#define NE 800000
#define DD 96
#define BN_EPS 1e-5

typedef __attribute__((ext_vector_type(8))) short short8v;
typedef __attribute__((ext_vector_type(4))) float float4v;

__device__ inline float bf2f(unsigned u) { return __uint_as_float(u << 16); }
__device__ inline unsigned short f2bf(float f) {
  unsigned u = __float_as_uint(f);
  return (unsigned short)((u + 0x7FFF + ((u >> 16) & 1)) >> 16);
}
__device__ inline void unpack8(uint4 v, float* f) {
  f[0] = bf2f(v.x & 0xffff); f[1] = bf2f(v.x >> 16);
  f[2] = bf2f(v.y & 0xffff); f[3] = bf2f(v.y >> 16);
  f[4] = bf2f(v.z & 0xffff); f[5] = bf2f(v.z >> 16);
  f[6] = bf2f(v.w & 0xffff); f[7] = bf2f(v.w >> 16);
}
__device__ inline uint4 pack8(const float* f) {
  uint4 v;
  v.x = (unsigned)f2bf(f[0]) | ((unsigned)f2bf(f[1]) << 16);
  v.y = (unsigned)f2bf(f[2]) | ((unsigned)f2bf(f[3]) << 16);
  v.z = (unsigned)f2bf(f[4]) | ((unsigned)f2bf(f[5]) << 16);
  v.w = (unsigned)f2bf(f[6]) | ((unsigned)f2bf(f[7]) << 16);
  return v;
}

// ============ fp32 -> bf16 convert (8 elems/thread) ============
__global__ __launch_bounds__(256) void f2bf_k(const float* __restrict__ in,
                                              unsigned short* __restrict__ out,
                                              int n8) {
  int t = blockIdx.x * 256 + threadIdx.x;
  if (t >= n8) return;
  const float4* p = (const float4*)in + 2 * t;
  float4 a = p[0], b = p[1];
  float f[8] = {a.x, a.y, a.z, a.w, b.x, b.y, b.z, b.w};
  ((uint4*)out)[t] = pack8(f);
}

// ============ CSR build ============
__global__ __launch_bounds__(256) void hist_k(const int* __restrict__ dst,
                                              int* __restrict__ counts) {
  int e = blockIdx.x * 256 + threadIdx.x;
  if (e < NE) atomicAdd(&counts[dst[e]], 1);
}

__global__ void exscan_k(const int* __restrict__ counts,
                         int* __restrict__ rowstart) {
  __shared__ int part[1024];
  int tid = threadIdx.x;
  const int CH = (NN + 1023) / 1024;
  int lo = tid * CH, hi = min(lo + CH, NN);
  int s = 0;
  for (int i = lo; i < hi; i++) s += counts[i];
  part[tid] = s;
  __syncthreads();
  for (int off = 1; off < 1024; off <<= 1) {
    int t = (tid >= off) ? part[tid - off] : 0;
    __syncthreads();
    part[tid] += t;
    __syncthreads();
  }
  int run = (tid == 0) ? 0 : part[tid - 1];
  for (int i = lo; i < hi; i++) {
    rowstart[i] = run;
    run += counts[i];
  }
  if (tid == 1023) rowstart[NN] = run;
}

__global__ __launch_bounds__(256) void scatter_k(
    const int* __restrict__ src, const int* __restrict__ dst,
    const float* __restrict__ ea, const int* __restrict__ rowstart,
    int* __restrict__ cursor, int2* __restrict__ pack) {
  int e = blockIdx.x * 256 + threadIdx.x;
  if (e >= NE) return;
  int d = dst[e];
  int p = rowstart[d] + atomicAdd(&cursor[d], 1);
  int2 v;
  v.x = src[e];
  v.y = __float_as_int(ea[e]);
  pack[p] = v;
}

// ===== CSR aggregation (bf16): thread = (node, 8 feats) =====
__global__ __launch_bounds__(256) void agg_bf16(
    const unsigned short* __restrict__ xin, const float* __restrict__ lw,
    const float* __restrict__ lb, const int* __restrict__ rowstart,
    const int2* __restrict__ pack, unsigned short* __restrict__ out) {
  int t = blockIdx.x * 256 + threadIdx.x;
  if (t >= NN * 12) return;
  int n = t / 12, c8 = t - n * 12;
  float lwv[8], lbv[8], acc[8];
#pragma unroll
  for (int i = 0; i < 8; i++) {
    lwv[i] = lw[c8 * 8 + i];
    lbv[i] = lb[c8 * 8 + i];
  }
  uint4 xo = *(const uint4*)(xin + (size_t)n * DD + c8 * 8);
  unpack8(xo, acc);
  int beg = rowstart[n], end = rowstart[n + 1];
  for (int i = beg; i < end; i++) {
    int2 p = pack[i];
    float ev = __int_as_float(p.y);
    uint4 xv = *(const uint4*)(xin + (size_t)p.x * DD + c8 * 8);
    float xs[8];
    unpack8(xv, xs);
#pragma unroll
    for (int j = 0; j < 8; j++)
      acc[j] += fmaxf(xs[j] + fmaf(ev, lwv[j], lbv[j]), 0.0f);
  }
  *(uint4*)(out + (size_t)n * DD + c8 * 8) = pack8(acc);
}

// ============ W prep: fold BN scale, convert bf16, swizzle to frags ========
// Frag layout: Wz[((kt*MT+ct)*64 + lane)*8 + j] = W[kt*32+(lane>>4)*8+j][ct*16+(lane&15)]
// bf[j] = b[j] + sum_k shift[k]*W[KF0+k][j]  (folded rows)
template <int KF0, int KC, int K, int M>
__global__ __launch_bounds__(256) void wprep(const float* __restrict__ W,
                                             const float* __restrict__ b,
                                             const float* __restrict__ coeff,
                                             unsigned short* __restrict__ Wz,
                                             float* __restrict__ bf) {
  constexpr int KT = K / 32, MT = M / 16;
  int t = blockIdx.x * 256 + threadIdx.x;
  if (t < KT * MT * 64) {
    int lane = t & 63, fr = t >> 6;
    int kt = fr / MT, ct = fr - kt * MT;
    int col = ct * 16 + (lane & 15);
    int k0 = kt * 32 + (lane >> 4) * 8;
    float f[8];
#pragma unroll
    for (int j = 0; j < 8; j++) {
      int k = k0 + j;
      float w = W[k * M + col];
      if (KC > 0 && k >= KF0 && k < KF0 + KC) w *= coeff[k - KF0];
      f[j] = w;
    }
    ((uint4*)Wz)[t] = pack8(f);
  } else if (t < KT * MT * 64 + M) {
    int j = t - KT * MT * 64;
    float acc = b[j];
    if (KC > 0)
      for (int k = 0; k < KC; k++) acc += coeff[KC + k] * W[(KF0 + k) * M + j];
    bf[j] = acc;
  }
}

// ============ MFMA GEMM + bias + relu + column stats ============
// 256 thr = 4 waves; wave owns 16-row tiles (grid-stride). A from bf16
// row-major (optionally concat of A1[K1], A2[K2]); B from swizzled Wz.
template <int K1, int K2, int M, bool OUTF32>
__global__ __launch_bounds__(256) void gemm_mfma(
    const unsigned short* __restrict__ A1,
    const unsigned short* __restrict__ A2,
    const unsigned short* __restrict__ Wz, const float* __restrict__ bias,
    void* __restrict__ hOut, double* __restrict__ stats) {
  constexpr int K = K1 + K2;
  constexpr int KT = K / 32;
  constexpr int MT = M / 16;
  constexpr int NT = NN / 16;  // 3125, exact
  int tid = threadIdx.x;
  int wave = tid >> 6, lane = tid & 63;
  int lr = lane & 15, lk = lane >> 4;

  float bj[MT], s[MT], q[MT];
#pragma unroll
  for (int ct = 0; ct < MT; ct++) {
    bj[ct] = bias[ct * 16 + lr];
    s[ct] = 0.f;
    q[ct] = 0.f;
  }

  for (int tt = blockIdx.x * 4 + wave; tt < NT; tt += gridDim.x * 4) {
    float4v acc[MT];
#pragma unroll
    for (int ct = 0; ct < MT; ct++) acc[ct] = (float4v){0.f, 0.f, 0.f, 0.f};

    const unsigned short* a1 = A1 + (size_t)(tt * 16 + lr) * K1 + lk * 8;
    const unsigned short* a2 =
        (K2 > 0) ? A2 + (size_t)(tt * 16 + lr) * K2 + lk * 8 : a1;
#pragma unroll
    for (int kt = 0; kt < KT; kt++) {
      short8v av;
      if (kt * 32 < K1)
        av = *reinterpret_cast<const short8v*>(a1 + kt * 32);
      else
        av = *reinterpret_cast<const short8v*>(a2 + (kt * 32 - K1));
#pragma unroll
      for (int ct = 0; ct < MT; ct++) {
        short8v bv = *reinterpret_cast<const short8v*>(
            Wz + ((size_t)(kt * MT + ct) * 64 + lane) * 8);
        acc[ct] =
            __builtin_amdgcn_mfma_f32_16x16x32_bf16(av, bv, acc[ct], 0, 0, 0);
      }
    }
#pragma unroll
    for (int ct = 0; ct < MT; ct++) {
#pragma unroll
      for (int i = 0; i < 4; i++) {
        float o = fmaxf(acc[ct][i] + bj[ct], 0.f);
        size_t row = (size_t)tt * 16 + lk * 4 + i;
        if (OUTF32)
          ((float*)hOut)[row * M + ct * 16 + lr] = o;
        else
          ((unsigned short*)hOut)[row * M + ct * 16 + lr] = f2bf(o);
        s[ct] += o;
        q[ct] += o * o;
      }
    }
  }

  __shared__ float sred[4][M], qred[4][M];
#pragma unroll
  for (int ct = 0; ct < MT; ct++) {
    float ss = s[ct], qq = q[ct];
    ss += __shfl_xor(ss, 16);
    ss += __shfl_xor(ss, 32);
    qq += __shfl_xor(qq, 16);
    qq += __shfl_xor(qq, 32);
    if (lk == 0) {
      sred[wave][ct * 16 + lr] = ss;
      qred[wave][ct * 16 + lr] = qq;
    }
  }
  __syncthreads();
  if (tid < M) {
    double ss = (double)sred[0][tid] + sred[1][tid] + sred[2][tid] + sred[3][tid];
    double qq = (double)qred[0][tid] + qred[1][tid] + qred[2][tid] + qred[3][tid];
    atomicAdd(&stats[tid], ss);
    atomicAdd(&stats[M + tid], qq);
  }
}

// ============ BN coeffs ============
template <int M>
__global__ void bn_coeffs(const double* __restrict__ stats,
                          const float* __restrict__ g,
                          const float* __restrict__ beta,
                          float* __restrict__ coeff) {
  int j = threadIdx.x;
  if (j >= M) return;
  double mu = stats[j] / (double)NN;
  double var = stats[M + j] / (double)NN - mu * mu;
  double inv = 1.0 / sqrt(var + (double)BN_EPS);
  double scale = (double)g[j] * inv;
  coeff[j] = (float)scale;
  coeff[M + j] = (float)((double)beta[j] - mu * scale);
}

// ============ BN normalize bf16->bf16, M=96 (8 cols/thread) ============
__global__ __launch_bounds__(256) void bnnorm96_bf16(
    const unsigned short* __restrict__ h, const float* __restrict__ coeff,
    unsigned short* __restrict__ out) {
  int t = blockIdx.x * 256 + threadIdx.x;
  if (t >= NN * 12) return;
  int c8 = t % 12;
  uint4 v = ((const uint4*)h)[t];
  float f[8];
  unpack8(v, f);
#pragma unroll
  for (int j = 0; j < 8; j++)
    f[j] = fmaf(f[j], coeff[c8 * 8 + j], coeff[96 + c8 * 8 + j]);
  ((uint4*)out)[t] = pack8(f);
}

// ============ BN normalize fp32 (final, M=16) ============
template <int M>
__global__ __launch_bounds__(256) void bn_norm4(const float4* __restrict__ h,
                                                const float* __restrict__ coeff,
                                                float4* __restrict__ out) {
  int t = blockIdx.x * 256 + threadIdx.x;
  if (t >= NN * M / 4) return;
  float4 v = h[t];
  int j0 = (4 * t) % M;
  float4 o;
  o.x = fmaf(v.x, coeff[j0 + 0], coeff[M + j0 + 0]);
  o.y = fmaf(v.y, coeff[j0 + 1], coeff[M + j0 + 1]);
  o.z = fmaf(v.z, coeff[j0 + 2], coeff[M + j0 + 2]);
  o.w = fmaf(v.w, coeff[j0 + 3], coeff[M + j0 + 3]);
  out[t] = o;
}

static inline char* alignup(char* p, size_t a) {
  return (char*)(((uintptr_t)p + a - 1) & ~(uintptr_t)(a - 1));
}

extern "C" void kernel_launch(void* const* d_in, const int* in_sizes, int n_in,
                              void* d_out, int out_size, void* d_ws,
                              size_t ws_size, hipStream_t stream) {
  const float* x = (const float*)d_in[0];
  const float* ea = (const float*)d_in[1];
  const int* ei = (const int*)d_in[2];
  const int* src = ei;
  const int* dst = ei + NE;
  const float* lin_w = (const float*)d_in[3];
  const float* lin_b = (const float*)d_in[4];
  const float* c1_w = (const float*)d_in[5];
  const float* c1_b = (const float*)d_in[6];
  const float* c1_g = (const float*)d_in[7];
  const float* c1_be = (const float*)d_in[8];
  const float* c2_w = (const float*)d_in[9];
  const float* c2_b = (const float*)d_in[10];
  const float* c2_g = (const float*)d_in[11];
  const float* c2_be = (const float*)d_in[12];
  const float* l1_w = (const float*)d_in[13];
  const float* l1_b = (const float*)d_in[14];
  const float* l1_g = (const float*)d_in[15];
  const float* l1_be = (const float*)d_in[16];
  const float* ma_w = (const float*)d_in[17];
  const float* ma_b = (const float*)d_in[18];
  const float* ma_g = (const float*)d_in[19];
  const float* ma_be = (const float*)d_in[20];
  const float* mb_w = (const float*)d_in[21];
  const float* mb_b = (const float*)d_in[22];
  const float* mb_g = (const float*)d_in[23];
  const float* mb_be = (const float*)d_in[24];

  typedef unsigned short us;
  char* p = (char*)d_ws;
  us* xb = (us*)p;   p += (size_t)NN * 96 * 2;   // x bf16
  us* Ab = (us*)p;   p += (size_t)NN * 96 * 2;   // agg out (conv1, conv2)
  us* H1 = (us*)p;   p += (size_t)NN * 96 * 2;
  us* X1 = (us*)p;   p += (size_t)NN * 96 * 2;
  us* H2 = (us*)p;   p += (size_t)NN * 64 * 2;
  us* H3 = (us*)p;   p += (size_t)NN * 96 * 2;
  us* H4 = (us*)p;   p += (size_t)NN * 96 * 2;
  float* H5 = (float*)p; p += (size_t)NN * 16 * 4;
  p = alignup(p, 256);
  us* Wz1 = (us*)p;  p += 3 * 6 * 64 * 8 * 2;
  us* Wz2 = (us*)p;  p += 3 * 4 * 64 * 8 * 2;
  us* Wz3 = (us*)p;  p += 5 * 6 * 64 * 8 * 2;
  us* Wz4 = (us*)p;  p += 3 * 6 * 64 * 8 * 2;
  us* Wz5 = (us*)p;  p += 3 * 1 * 64 * 8 * 2;
  p = alignup(p, 256);
  float* bf1 = (float*)p; p += 96 * 4;
  float* bf2 = (float*)p; p += 64 * 4;
  float* bf3 = (float*)p; p += 96 * 4;
  float* bf4 = (float*)p; p += 96 * 4;
  float* bf5 = (float*)p; p += 16 * 4;
  float* coeffs = (float*)p; p += 5 * 192 * 4;
  p = alignup(p, 256);
  char* zbase = p;
  int* counts = (int*)p;  p += (size_t)NN * 4;
  int* cursor = (int*)p;  p += (size_t)NN * 4;
  double* stats = (double*)p; p += (size_t)5 * 192 * 8;
  size_t zbytes = (size_t)(p - zbase);
  int* rowstart = (int*)p; p += (size_t)(NN + 1) * 4;
  p = alignup(p, 8);
  int2* pack = (int2*)p;  p += (size_t)NE * 8;

  float* c1 = coeffs;
  float* c2 = coeffs + 192;
  float* c3 = coeffs + 384;
  float* c4 = coeffs + 576;
  float* c5 = coeffs + 768;

  hipMemsetAsync(zbase, 0, zbytes, stream);

  const int eb = (NE + 255) / 256;
  const int n12 = NN * 12;
  const int b12 = (n12 + 255) / 256;
  const int GG = 256;  // gemm grid

  // ---- prep ----
  f2bf_k<<<b12, 256, 0, stream>>>(x, xb, n12);
  hist_k<<<eb, 256, 0, stream>>>(dst, counts);
  exscan_k<<<1, 1024, 0, stream>>>(counts, rowstart);
  scatter_k<<<eb, 256, 0, stream>>>(src, dst, ea, rowstart, cursor, pack);

  // ---- conv1 ----
  agg_bf16<<<b12, 256, 0, stream>>>(xb, lin_w, lin_b, rowstart, pack, Ab);
  wprep<0, 0, 96, 96><<<5, 256, 0, stream>>>(c1_w, c1_b, nullptr, Wz1, bf1);
  gemm_mfma<96, 0, 96, false><<<GG, 256, 0, stream>>>(Ab, nullptr, Wz1, bf1,
                                                      H1, stats);
  bn_coeffs<96><<<1, 96, 0, stream>>>(stats, c1_g, c1_be, c1);
  bnnorm96_bf16<<<b12, 256, 0, stream>>>(H1, c1, X1);

  // ---- conv2 ----
  agg_bf16<<<b12, 256, 0, stream>>>(X1, lin_w, lin_b, rowstart, pack, Ab);
  wprep<0, 0, 96, 64><<<4, 256, 0, stream>>>(c2_w, c2_b, nullptr, Wz2, bf2);
  gemm_mfma<96, 0, 64, false><<<GG, 256, 0, stream>>>(Ab, nullptr, Wz2, bf2,
                                                      H2, stats + 192);
  bn_coeffs<64><<<1, 64, 0, stream>>>(stats + 192, c2_g, c2_be, c2);

  // ---- lin1 on concat([X1, H2(BN2 folded)]) ----
  wprep<96, 64, 160, 96><<<8, 256, 0, stream>>>(l1_w, l1_b, c2, Wz3, bf3);
  gemm_mfma<96, 64, 96, false><<<GG, 256, 0, stream>>>(X1, H2, Wz3, bf3, H3,
                                                       stats + 384);
  bn_coeffs<96><<<1, 96, 0, stream>>>(stats + 384, l1_g, l1_be, c3);

  // ---- mlp1a (BN3 folded) ----
  wprep<0, 96, 96, 96><<<5, 256, 0, stream>>>(ma_w, ma_b, c3, Wz4, bf4);
  gemm_mfma<96, 0, 96, false><<<GG, 256, 0, stream>>>(H3, nullptr, Wz4, bf4,
                                                      H4, stats + 576);
  bn_coeffs<96><<<1, 96, 0, stream>>>(stats + 576, ma_g, ma_be, c4);

  // ---- mlp1b (BN4 folded) -> fp32 H5 ----
  wprep<0, 96, 96, 16><<<1, 256, 0, stream>>>(mb_w, mb_b, c4, Wz5, bf5);
  gemm_mfma<96, 0, 16, true><<<GG, 256, 0, stream>>>(H4, nullptr, Wz5, bf5, H5,
                                                     stats + 768);
  bn_coeffs<16><<<1, 16, 0, stream>>>(stats + 768, mb_g, mb_be, c5);
  bn_norm4<16><<<(NN * 16 / 4 + 255) / 256, 256, 0, stream>>>(
      (const float4*)H5, c5, (float4*)d_out);
}

// Round 5
// 391.397 us; speedup vs baseline: 3.3315x; 1.1375x over previous
//
#include <hip/hip_runtime.h>

#define NN 50000
#define NE 800000
#define DD 96
#define BN_EPS 1e-5
#define NB 196  // ceil(NN/256)

typedef __attribute__((ext_vector_type(8))) short short8v;
typedef __attribute__((ext_vector_type(4))) float float4v;

__device__ inline float bf2f(unsigned u) { return __uint_as_float(u << 16); }
__device__ inline unsigned short f2bf(float f) {
  unsigned u = __float_as_uint(f);
  return (unsigned short)((u + 0x7FFF + ((u >> 16) & 1)) >> 16);
}
__device__ inline void unpack8(uint4 v, float* f) {
  f[0] = bf2f(v.x & 0xffff); f[1] = bf2f(v.x >> 16);
  f[2] = bf2f(v.y & 0xffff); f[3] = bf2f(v.y >> 16);
  f[4] = bf2f(v.z & 0xffff); f[5] = bf2f(v.z >> 16);
  f[6] = bf2f(v.w & 0xffff); f[7] = bf2f(v.w >> 16);
}
__device__ inline uint4 pack8(const float* f) {
  uint4 v;
  v.x = (unsigned)f2bf(f[0]) | ((unsigned)f2bf(f[1]) << 16);
  v.y = (unsigned)f2bf(f[2]) | ((unsigned)f2bf(f[3]) << 16);
  v.z = (unsigned)f2bf(f[4]) | ((unsigned)f2bf(f[5]) << 16);
  v.w = (unsigned)f2bf(f[6]) | ((unsigned)f2bf(f[7]) << 16);
  return v;
}

// ============ fp32 -> bf16 convert ============
__global__ __launch_bounds__(256) void f2bf_k(const float* __restrict__ in,
                                              unsigned short* __restrict__ out,
                                              int n8) {
  int t = blockIdx.x * 256 + threadIdx.x;
  if (t >= n8) return;
  const float4* p = (const float4*)in + 2 * t;
  float4 a = p[0], b = p[1];
  float f[8] = {a.x, a.y, a.z, a.w, b.x, b.y, b.z, b.w};
  ((uint4*)out)[t] = pack8(f);
}

// ============ CSR build ============
__global__ __launch_bounds__(256) void hist_k(const int* __restrict__ dst,
                                              int* __restrict__ counts) {
  int e = blockIdx.x * 256 + threadIdx.x;
  if (e < NE) atomicAdd(&counts[dst[e]], 1);
}

// multi-block exclusive scan of counts[NN] -> rowstart[NN+1]
__global__ __launch_bounds__(256) void scan_part(const int* __restrict__ counts,
                                                 int* __restrict__ bsum) {
  __shared__ int s[256];
  int tid = threadIdx.x;
  int i = blockIdx.x * 256 + tid;
  s[tid] = (i < NN) ? counts[i] : 0;
  __syncthreads();
  for (int st = 128; st > 0; st >>= 1) {
    if (tid < st) s[tid] += s[tid + st];
    __syncthreads();
  }
  if (tid == 0) bsum[blockIdx.x] = s[0];
}

__global__ __launch_bounds__(256) void scan_top(const int* __restrict__ bsum,
                                                int* __restrict__ boff) {
  __shared__ int s[256];
  int tid = threadIdx.x;
  int v = (tid < NB) ? bsum[tid] : 0;
  s[tid] = v;
  __syncthreads();
  for (int off = 1; off < 256; off <<= 1) {
    int t = (tid >= off) ? s[tid - off] : 0;
    __syncthreads();
    s[tid] += t;
    __syncthreads();
  }
  if (tid < NB) boff[tid] = s[tid] - v;  // exclusive
}

__global__ __launch_bounds__(256) void scan_apply(
    const int* __restrict__ counts, const int* __restrict__ boff,
    int* __restrict__ rowstart) {
  __shared__ int s[256];
  int tid = threadIdx.x;
  int i = blockIdx.x * 256 + tid;
  int v = (i < NN) ? counts[i] : 0;
  s[tid] = v;
  __syncthreads();
  for (int off = 1; off < 256; off <<= 1) {
    int t = (tid >= off) ? s[tid - off] : 0;
    __syncthreads();
    s[tid] += t;
    __syncthreads();
  }
  if (i < NN) rowstart[i] = boff[blockIdx.x] + s[tid] - v;
  if (i == 0) rowstart[NN] = NE;
}

__global__ __launch_bounds__(256) void scatter_k(
    const int* __restrict__ src, const int* __restrict__ dst,
    const float* __restrict__ ea, const int* __restrict__ rowstart,
    int* __restrict__ cursor, int2* __restrict__ pack) {
  int e = blockIdx.x * 256 + threadIdx.x;
  if (e >= NE) return;
  int d = dst[e];
  int p = rowstart[d] + atomicAdd(&cursor[d], 1);
  int2 v;
  v.x = src[e];
  v.y = __float_as_int(ea[e]);
  pack[p] = v;
}

// ===== CSR aggregation (bf16): thread = (node, 8 feats) =====
__global__ __launch_bounds__(256) void agg_bf16(
    const unsigned short* __restrict__ xin, const float* __restrict__ lw,
    const float* __restrict__ lb, const int* __restrict__ rowstart,
    const int2* __restrict__ pack, unsigned short* __restrict__ out) {
  int t = blockIdx.x * 256 + threadIdx.x;
  if (t >= NN * 12) return;
  int n = t / 12, c8 = t - n * 12;
  float lwv[8], lbv[8], acc[8];
#pragma unroll
  for (int i = 0; i < 8; i++) {
    lwv[i] = lw[c8 * 8 + i];
    lbv[i] = lb[c8 * 8 + i];
  }
  uint4 xo = *(const uint4*)(xin + (size_t)n * DD + c8 * 8);
  unpack8(xo, acc);
  int beg = rowstart[n], end = rowstart[n + 1];
  for (int i = beg; i < end; i++) {
    int2 p = pack[i];
    float ev = __int_as_float(p.y);
    uint4 xv = *(const uint4*)(xin + (size_t)p.x * DD + c8 * 8);
    float xs[8];
    unpack8(xv, xs);
#pragma unroll
    for (int j = 0; j < 8; j++)
      acc[j] += fmaxf(xs[j] + fmaf(ev, lwv[j], lbv[j]), 0.0f);
  }
  *(uint4*)(out + (size_t)n * DD + c8 * 8) = pack8(acc);
}

// ===== same, with BN affine (coeff) applied to h on the fly =====
// x1 = s*h + t; out = x1[n] + sum relu(s*h[src] + (t + lb) + ev*lw)
__global__ __launch_bounds__(256) void agg_bf16_norm(
    const unsigned short* __restrict__ h, const float* __restrict__ coeff,
    const float* __restrict__ lw, const float* __restrict__ lb,
    const int* __restrict__ rowstart, const int2* __restrict__ pack,
    unsigned short* __restrict__ out) {
  int t = blockIdx.x * 256 + threadIdx.x;
  if (t >= NN * 12) return;
  int n = t / 12, c8 = t - n * 12;
  float sc[8], tlb[8], tsh[8], lwv[8], acc[8];
#pragma unroll
  for (int i = 0; i < 8; i++) {
    sc[i] = coeff[c8 * 8 + i];
    tsh[i] = coeff[96 + c8 * 8 + i];
    tlb[i] = tsh[i] + lb[c8 * 8 + i];
    lwv[i] = lw[c8 * 8 + i];
  }
  uint4 xo = *(const uint4*)(h + (size_t)n * DD + c8 * 8);
  float f[8];
  unpack8(xo, f);
#pragma unroll
  for (int i = 0; i < 8; i++) acc[i] = fmaf(sc[i], f[i], tsh[i]);
  int beg = rowstart[n], end = rowstart[n + 1];
  for (int i = beg; i < end; i++) {
    int2 p = pack[i];
    float ev = __int_as_float(p.y);
    uint4 xv = *(const uint4*)(h + (size_t)p.x * DD + c8 * 8);
    float xs[8];
    unpack8(xv, xs);
#pragma unroll
    for (int j = 0; j < 8; j++) {
      float base = fmaf(ev, lwv[j], tlb[j]);
      acc[j] += fmaxf(fmaf(sc[j], xs[j], base), 0.0f);
    }
  }
  *(uint4*)(out + (size_t)n * DD + c8 * 8) = pack8(acc);
}

// ============ W prep: fold BN scales (two regions), bf16, swizzle ========
// Rows [0,KA) scaled by cA (layout scale[0..KA), shift[KA..2KA));
// rows [KA,KA+KB) scaled by cB (scale[0..KB), shift[KB..2KB)).
template <int K, int M, int KA, int KB>
__global__ __launch_bounds__(256) void wprep(const float* __restrict__ W,
                                             const float* __restrict__ b,
                                             const float* __restrict__ cA,
                                             const float* __restrict__ cB,
                                             unsigned short* __restrict__ Wz,
                                             float* __restrict__ bf) {
  constexpr int KT = K / 32, MT = M / 16;
  int t = blockIdx.x * 256 + threadIdx.x;
  if (t < KT * MT * 64) {
    int lane = t & 63, fr = t >> 6;
    int kt = fr / MT, ct = fr - kt * MT;
    int col = ct * 16 + (lane & 15);
    int k0 = kt * 32 + (lane >> 4) * 8;
    float f[8];
#pragma unroll
    for (int j = 0; j < 8; j++) {
      int k = k0 + j;
      float w = W[k * M + col];
      if (KA > 0 && k < KA) w *= cA[k];
      if (KB > 0 && k >= KA && k < KA + KB) w *= cB[k - KA];
      f[j] = w;
    }
    ((uint4*)Wz)[t] = pack8(f);
  } else if (t < KT * MT * 64 + M) {
    int j = t - KT * MT * 64;
    float acc = b[j];
    if (KA > 0)
      for (int k = 0; k < KA; k++) acc += cA[KA + k] * W[k * M + j];
    if (KB > 0)
      for (int k = 0; k < KB; k++) acc += cB[KB + k] * W[(KA + k) * M + j];
    bf[j] = acc;
  }
}

// ============ MFMA GEMM + bias + relu + column stats ============
template <int K1, int K2, int M, bool OUTF32>
__global__ __launch_bounds__(256) void gemm_mfma(
    const unsigned short* __restrict__ A1,
    const unsigned short* __restrict__ A2,
    const unsigned short* __restrict__ Wz, const float* __restrict__ bias,
    void* __restrict__ hOut, double* __restrict__ stats) {
  constexpr int K = K1 + K2;
  constexpr int KT = K / 32;
  constexpr int MT = M / 16;
  constexpr int NT = NN / 16;  // 3125
  int tid = threadIdx.x;
  int wave = tid >> 6, lane = tid & 63;
  int lr = lane & 15, lk = lane >> 4;

  float bj[MT], s[MT], q[MT];
#pragma unroll
  for (int ct = 0; ct < MT; ct++) {
    bj[ct] = bias[ct * 16 + lr];
    s[ct] = 0.f;
    q[ct] = 0.f;
  }

  for (int tt = blockIdx.x * 4 + wave; tt < NT; tt += gridDim.x * 4) {
    float4v acc[MT];
#pragma unroll
    for (int ct = 0; ct < MT; ct++) acc[ct] = (float4v){0.f, 0.f, 0.f, 0.f};

    const unsigned short* a1 = A1 + (size_t)(tt * 16 + lr) * K1 + lk * 8;
    const unsigned short* a2 =
        (K2 > 0) ? A2 + (size_t)(tt * 16 + lr) * K2 + lk * 8 : a1;
#pragma unroll
    for (int kt = 0; kt < KT; kt++) {
      short8v av;
      if (kt * 32 < K1)
        av = *reinterpret_cast<const short8v*>(a1 + kt * 32);
      else
        av = *reinterpret_cast<const short8v*>(a2 + (kt * 32 - K1));
#pragma unroll
      for (int ct = 0; ct < MT; ct++) {
        short8v bv = *reinterpret_cast<const short8v*>(
            Wz + ((size_t)(kt * MT + ct) * 64 + lane) * 8);
        acc[ct] =
            __builtin_amdgcn_mfma_f32_16x16x32_bf16(av, bv, acc[ct], 0, 0, 0);
      }
    }
#pragma unroll
    for (int ct = 0; ct < MT; ct++) {
#pragma unroll
      for (int i = 0; i < 4; i++) {
        float o = fmaxf(acc[ct][i] + bj[ct], 0.f);
        size_t row = (size_t)tt * 16 + lk * 4 + i;
        if (OUTF32)
          ((float*)hOut)[row * M + ct * 16 + lr] = o;
        else
          ((unsigned short*)hOut)[row * M + ct * 16 + lr] = f2bf(o);
        s[ct] += o;
        q[ct] += o * o;
      }
    }
  }

  __shared__ float sred[4][M], qred[4][M];
#pragma unroll
  for (int ct = 0; ct < MT; ct++) {
    float ss = s[ct], qq = q[ct];
    ss += __shfl_xor(ss, 16);
    ss += __shfl_xor(ss, 32);
    qq += __shfl_xor(qq, 16);
    qq += __shfl_xor(qq, 32);
    if (lk == 0) {
      sred[wave][ct * 16 + lr] = ss;
      qred[wave][ct * 16 + lr] = qq;
    }
  }
  __syncthreads();
  if (tid < M) {
    double ss = (double)sred[0][tid] + sred[1][tid] + sred[2][tid] + sred[3][tid];
    double qq = (double)qred[0][tid] + qred[1][tid] + qred[2][tid] + qred[3][tid];
    atomicAdd(&stats[tid], ss);
    atomicAdd(&stats[M + tid], qq);
  }
}

// ============ BN coeffs ============
template <int M>
__global__ void bn_coeffs(const double* __restrict__ stats,
                          const float* __restrict__ g,
                          const float* __restrict__ beta,
                          float* __restrict__ coeff) {
  int j = threadIdx.x;
  if (j >= M) return;
  double mu = stats[j] / (double)NN;
  double var = stats[M + j] / (double)NN - mu * mu;
  double inv = 1.0 / sqrt(var + (double)BN_EPS);
  double scale = (double)g[j] * inv;
  coeff[j] = (float)scale;
  coeff[M + j] = (float)((double)beta[j] - mu * scale);
}

// ============ final: BN coeffs (inline) + normalize, M=16, fp32 ============
__global__ __launch_bounds__(256) void bnout(const float4* __restrict__ h,
                                             const double* __restrict__ stats,
                                             const float* __restrict__ g,
                                             const float* __restrict__ beta,
                                             float4* __restrict__ out) {
  __shared__ float sc[16], sh[16];
  int tid = threadIdx.x;
  if (tid < 16) {
    double mu = stats[tid] / (double)NN;
    double var = stats[16 + tid] / (double)NN - mu * mu;
    double inv = 1.0 / sqrt(var + (double)BN_EPS);
    double scale = (double)g[tid] * inv;
    sc[tid] = (float)scale;
    sh[tid] = (float)((double)beta[tid] - mu * scale);
  }
  __syncthreads();
  int t = blockIdx.x * 256 + tid;
  if (t >= NN * 4) return;
  float4 v = h[t];
  int j0 = (4 * t) & 15;
  float4 o;
  o.x = fmaf(v.x, sc[j0 + 0], sh[j0 + 0]);
  o.y = fmaf(v.y, sc[j0 + 1], sh[j0 + 1]);
  o.z = fmaf(v.z, sc[j0 + 2], sh[j0 + 2]);
  o.w = fmaf(v.w, sc[j0 + 3], sh[j0 + 3]);
  out[t] = o;
}

static inline char* alignup(char* p, size_t a) {
  return (char*)(((uintptr_t)p + a - 1) & ~(uintptr_t)(a - 1));
}

extern "C" void kernel_launch(void* const* d_in, const int* in_sizes, int n_in,
                              void* d_out, int out_size, void* d_ws,
                              size_t ws_size, hipStream_t stream) {
  const float* x = (const float*)d_in[0];
  const float* ea = (const float*)d_in[1];
  const int* ei = (const int*)d_in[2];
  const int* src = ei;
  const int* dst = ei + NE;
  const float* lin_w = (const float*)d_in[3];
  const float* lin_b = (const float*)d_in[4];
  const float* c1_w = (const float*)d_in[5];
  const float* c1_b = (const float*)d_in[6];
  const float* c1_g = (const float*)d_in[7];
  const float* c1_be = (const float*)d_in[8];
  const float* c2_w = (const float*)d_in[9];
  const float* c2_b = (const float*)d_in[10];
  const float* c2_g = (const float*)d_in[11];
  const float* c2_be = (const float*)d_in[12];
  const float* l1_w = (const float*)d_in[13];
  const float* l1_b = (const float*)d_in[14];
  const float* l1_g = (const float*)d_in[15];
  const float* l1_be = (const float*)d_in[16];
  const float* ma_w = (const float*)d_in[17];
  const float* ma_b = (const float*)d_in[18];
  const float* ma_g = (const float*)d_in[19];
  const float* ma_be = (const float*)d_in[20];
  const float* mb_w = (const float*)d_in[21];
  const float* mb_b = (const float*)d_in[22];
  const float* mb_g = (const float*)d_in[23];
  const float* mb_be = (const float*)d_in[24];

  typedef unsigned short us;
  char* p = (char*)d_ws;
  us* xb = (us*)p;   p += (size_t)NN * 96 * 2;
  us* Ab = (us*)p;   p += (size_t)NN * 96 * 2;
  us* H1 = (us*)p;   p += (size_t)NN * 96 * 2;
  us* H2 = (us*)p;   p += (size_t)NN * 64 * 2;
  us* H3 = (us*)p;   p += (size_t)NN * 96 * 2;
  us* H4 = (us*)p;   p += (size_t)NN * 96 * 2;
  float* H5 = (float*)p; p += (size_t)NN * 16 * 4;
  p = alignup(p, 256);
  us* Wz1 = (us*)p;  p += 3 * 6 * 64 * 8 * 2;
  us* Wz2 = (us*)p;  p += 3 * 4 * 64 * 8 * 2;
  us* Wz3 = (us*)p;  p += 5 * 6 * 64 * 8 * 2;
  us* Wz4 = (us*)p;  p += 3 * 6 * 64 * 8 * 2;
  us* Wz5 = (us*)p;  p += 3 * 1 * 64 * 8 * 2;
  p = alignup(p, 256);
  float* bf1 = (float*)p; p += 96 * 4;
  float* bf2 = (float*)p; p += 64 * 4;
  float* bf3 = (float*)p; p += 96 * 4;
  float* bf4 = (float*)p; p += 96 * 4;
  float* bf5 = (float*)p; p += 16 * 4;
  float* coeffs = (float*)p; p += 4 * 192 * 4;
  p = alignup(p, 256);
  char* zbase = p;
  int* counts = (int*)p;  p += (size_t)NN * 4;
  int* cursor = (int*)p;  p += (size_t)NN * 4;
  double* stats = (double*)p; p += (size_t)5 * 192 * 8;
  size_t zbytes = (size_t)(p - zbase);
  int* rowstart = (int*)p; p += (size_t)(NN + 1) * 4;
  int* bsum = (int*)p;    p += 256 * 4;
  int* boff = (int*)p;    p += 256 * 4;
  p = alignup(p, 8);
  int2* pack = (int2*)p;  p += (size_t)NE * 8;

  float* c1 = coeffs;
  float* c2 = coeffs + 192;
  float* c3 = coeffs + 384;
  float* c4 = coeffs + 576;

  hipMemsetAsync(zbase, 0, zbytes, stream);

  const int eb = (NE + 255) / 256;
  const int n12 = NN * 12;
  const int b12 = (n12 + 255) / 256;
  const int GG = 512;

  // ---- prep ----
  f2bf_k<<<b12, 256, 0, stream>>>(x, xb, n12);
  hist_k<<<eb, 256, 0, stream>>>(dst, counts);
  scan_part<<<NB, 256, 0, stream>>>(counts, bsum);
  scan_top<<<1, 256, 0, stream>>>(bsum, boff);
  scan_apply<<<NB, 256, 0, stream>>>(counts, boff, rowstart);
  scatter_k<<<eb, 256, 0, stream>>>(src, dst, ea, rowstart, cursor, pack);

  // ---- conv1 ----
  agg_bf16<<<b12, 256, 0, stream>>>(xb, lin_w, lin_b, rowstart, pack, Ab);
  wprep<96, 96, 0, 0><<<5, 256, 0, stream>>>(c1_w, c1_b, nullptr, nullptr, Wz1,
                                             bf1);
  gemm_mfma<96, 0, 96, false><<<GG, 256, 0, stream>>>(Ab, nullptr, Wz1, bf1,
                                                      H1, stats);
  bn_coeffs<96><<<1, 96, 0, stream>>>(stats, c1_g, c1_be, c1);

  // ---- conv2 (BN1 applied on the fly to H1) ----
  agg_bf16_norm<<<b12, 256, 0, stream>>>(H1, c1, lin_w, lin_b, rowstart, pack,
                                         Ab);
  wprep<96, 64, 0, 0><<<4, 256, 0, stream>>>(c2_w, c2_b, nullptr, nullptr, Wz2,
                                             bf2);
  gemm_mfma<96, 0, 64, false><<<GG, 256, 0, stream>>>(Ab, nullptr, Wz2, bf2,
                                                      H2, stats + 192);
  bn_coeffs<64><<<1, 64, 0, stream>>>(stats + 192, c2_g, c2_be, c2);

  // ---- lin1 on concat([H1(BN1 folded), H2(BN2 folded)]) ----
  wprep<160, 96, 96, 64><<<8, 256, 0, stream>>>(l1_w, l1_b, c1, c2, Wz3, bf3);
  gemm_mfma<96, 64, 96, false><<<GG, 256, 0, stream>>>(H1, H2, Wz3, bf3, H3,
                                                       stats + 384);
  bn_coeffs<96><<<1, 96, 0, stream>>>(stats + 384, l1_g, l1_be, c3);

  // ---- mlp1a (BN3 folded) ----
  wprep<96, 96, 96, 0><<<5, 256, 0, stream>>>(ma_w, ma_b, c3, nullptr, Wz4,
                                              bf4);
  gemm_mfma<96, 0, 96, false><<<GG, 256, 0, stream>>>(H3, nullptr, Wz4, bf4,
                                                      H4, stats + 576);
  bn_coeffs<96><<<1, 96, 0, stream>>>(stats + 576, ma_g, ma_be, c4);

  // ---- mlp1b (BN4 folded) -> H5 fp32, then fused BN5+write ----
  wprep<96, 16, 96, 0><<<1, 256, 0, stream>>>(mb_w, mb_b, c4, nullptr, Wz5,
                                              bf5);
  gemm_mfma<96, 0, 16, true><<<GG, 256, 0, stream>>>(H4, nullptr, Wz5, bf5, H5,
                                                     stats + 768);
  bnout<<<(NN * 4 + 255) / 256, 256, 0, stream>>>(
      (const float4*)H5, stats + 768, mb_g, mb_be, (float4*)d_out);
}